// Round 6
// baseline (227.081 us; speedup 1.0000x reference)
//
#include <hip/hip_runtime.h>
#include <stdint.h>

typedef float f32x4 __attribute__((ext_vector_type(4)));
typedef __bf16 bfrag __attribute__((ext_vector_type(8)));
typedef unsigned short us4 __attribute__((ext_vector_type(4)));

__device__ __forceinline__ unsigned short f2bf(float f) {
  unsigned u = __float_as_uint(f);
  u += 0x7fff + ((u >> 16) & 1);   // RNE
  return (unsigned short)(u >> 16);
}
__device__ __forceinline__ float bf2f(unsigned short s) {
  return __uint_as_float(((unsigned)s) << 16);
}

typedef __attribute__((address_space(3))) void lds_vp;
typedef __attribute__((address_space(1))) void gl_vp;
__device__ __forceinline__ void gload16(const void* g, void* l) {
  __builtin_amdgcn_global_load_lds((const gl_vp*)g, (lds_vp*)l, 16, 0, 0);
}

// ---------------- kernel 0: transpose+convert weights to bf16 ----------------
__global__ __launch_bounds__(256)
void conv_w_k(const float* __restrict__ Wg, const float* __restrict__ Wb,
              unsigned short* __restrict__ WgT, unsigned short* __restrict__ WbT) {
  int i = blockIdx.x * 256 + threadIdx.x;
  if (i < 512 * 256) { int k = i >> 8, c = i & 255; WgT[c * 512 + k] = f2bf(Wg[i]); }
  if (i < 256 * 256) { int k = i >> 8, c = i & 255; WbT[c * 256 + k] = f2bf(Wb[i]); }
}

// ---------------- fused1: register-direct GEMM + adj epilogue ----------------
// BM=128 (8 batches), BN=256. 8 waves (wm 0..1 x wn 0..3), wave tile 64x64,
// acc[4][4]. NO LDS staging, NO barriers in K-loop: A and B fragments loaded
// straight from global (A lines shared 4 lanes/line; B is L2-hot 256KB).
// LDS (64KB) only for the sf epilogue buffer -> 2 blocks/CU, 16 waves/CU.
__global__ __launch_bounds__(512, 4)
void fused1_k(const float* __restrict__ A, const unsigned short* __restrict__ Bt,
              const float* __restrict__ adj, const float* __restrict__ b_gcn,
              const float* __restrict__ prelu_a,
              float* __restrict__ Cout, float* __restrict__ Hmv) {
  __shared__ unsigned short sf[128 * 256];   // 64 KB
  const int t = threadIdx.x;
  const int lane = t & 63;
  const int wid = t >> 6;
  const int wm = wid >> 2, wn = wid & 3;
  const int lrow = lane & 15, lgrp = lane >> 4;
  const int wg = blockIdx.x;

  // this lane's A row (for all 4 m-frags) and B col base, offset by lgrp*8 in k
  const float* a0 = A + (size_t)(wg * 128 + wm * 64 + lrow) * 512 + lgrp * 8;
  const unsigned short* b0 = Bt + (size_t)(wn * 64 + lrow) * 512 + lgrp * 8;

  f32x4 acc[4][4];
#pragma unroll
  for (int m = 0; m < 4; m++)
#pragma unroll
    for (int n = 0; n < 4; n++) acc[m][n] = (f32x4)0.0f;

#pragma unroll 2
  for (int kc = 0; kc < 8; ++kc) {
#pragma unroll
    for (int kk = 0; kk < 2; kk++) {
      const int ko = kc * 64 + kk * 32;
      bfrag bfv[4];
#pragma unroll
      for (int n = 0; n < 4; n++)
        bfv[n] = *(const bfrag*)(b0 + (size_t)n * 16 * 512 + ko);
#pragma unroll
      for (int m = 0; m < 4; m++) {
        f32x4 lo = *(const f32x4*)(a0 + (size_t)m * 16 * 512 + ko);
        f32x4 hi = *(const f32x4*)(a0 + (size_t)m * 16 * 512 + ko + 4);
        bfrag am;
        am[0] = (__bf16)lo.x; am[1] = (__bf16)lo.y; am[2] = (__bf16)lo.z; am[3] = (__bf16)lo.w;
        am[4] = (__bf16)hi.x; am[5] = (__bf16)hi.y; am[6] = (__bf16)hi.z; am[7] = (__bf16)hi.w;
#pragma unroll
        for (int n = 0; n < 4; n++)
          acc[m][n] = __builtin_amdgcn_mfma_f32_16x16x32_bf16(am, bfv[n], acc[m][n], 0, 0, 0);
      }
    }
  }

  // --- epilogue: write acc tile into sf bf16 [128][256] ---
#pragma unroll
  for (int m = 0; m < 4; m++) {
    int row = wm * 64 + m * 16 + lgrp * 4;
#pragma unroll
    for (int n = 0; n < 4; n++) {
      int col = wn * 64 + n * 16 + lrow;
#pragma unroll
      for (int rr = 0; rr < 4; rr++)
        sf[(row + rr) * 256 + col] = f2bf(acc[m][n][rr]);
    }
  }
  __syncthreads();

  // --- wave wid handles batch wg*8+wid: h1 = adj@sf + bg, PReLU, c, h_mv ---
  const float pa = prelu_a[0];
  const f32x4 bg = *(const f32x4*)(b_gcn + lane * 4);
  f32x4 sfr[16];
#pragma unroll
  for (int mm = 0; mm < 16; mm++) {
    us4 q = *(const us4*)(sf + (wid * 16 + mm) * 256 + lane * 4);
    f32x4 v;
    v.x = bf2f(q.x); v.y = bf2f(q.y); v.z = bf2f(q.z); v.w = bf2f(q.w);
    sfr[mm] = v;
  }
  const int b = wg * 8 + wid;
  const float* adjb = adj + (size_t)b * 256;
  f32x4 cacc = (f32x4)0.0f;
  f32x4 hmv = (f32x4)0.0f;
#pragma unroll
  for (int n = 0; n < 16; n++) {
    f32x4 a4 = (f32x4)0.0f;
#pragma unroll
    for (int m = 0; m < 16; m++) a4 += adjb[n * 16 + m] * sfr[m];
    a4 += bg;
    f32x4 hv;
    hv.x = a4.x >= 0.f ? a4.x : pa * a4.x;
    hv.y = a4.y >= 0.f ? a4.y : pa * a4.y;
    hv.z = a4.z >= 0.f ? a4.z : pa * a4.z;
    hv.w = a4.w >= 0.f ? a4.w : pa * a4.w;
    if (n < 15) cacc += hv; else hmv = hv;
  }
  cacc *= (1.0f / 15.0f);
  *(f32x4*)(Cout + (size_t)b * 256 + lane * 4) = cacc;
  *(f32x4*)(Hmv + (size_t)b * 256 + lane * 4) = hmv;
}

// ---------------- fused2: T = HMV@WbT (K=256) + bilinear + norms + loss ------
// BM=32 batches, BN=256, BK=32, grid 256. 8 waves (2x4), wave tile 16x64
// (acc[1][4]). LDS 2 x (A 4KB | B 16KB) = 40KB static, gload_lds staging.
__device__ __forceinline__ void stage2(const float* __restrict__ A,
                                       const unsigned short* __restrict__ Bt,
                                       char* buf, int wg, int kc, int t) {
  {
    int c = t & 255;                 // A: 32 rows x 32 f32 (4KB); dup per half
    int row = c >> 3, s = c & 7;
    int sp = s ^ (((row & 3) << 1) | ((row >> 2) & 1));
    gload16(A + (size_t)(wg * 32 + row) * 256 + kc * 32 + sp * 4, buf + c * 16);
  }
#pragma unroll
  for (int i = 0; i < 2; i++) {      // B: 256 cols x 32 bf16 (16KB)
    int c = i * 512 + t;
    int col = c >> 2, s = c & 3;
    int sp = s ^ ((col ^ (col >> 2)) & 3);
    gload16(Bt + (size_t)col * 256 + kc * 32 + sp * 8, buf + 4096 + c * 16);
  }
}

__global__ __launch_bounds__(512)
void fused2_k(const float* __restrict__ A, const unsigned short* __restrict__ Bt,
              const float* __restrict__ C, const float* __restrict__ Hmv,
              const float* __restrict__ b_bil, float* __restrict__ out) {
  __shared__ __align__(16) char sm2[40960];
  const int t = threadIdx.x;
  const int lane = t & 63;
  const int wid = t >> 6;
  const int wm = wid >> 2, wn = wid & 3;
  const int lrow = lane & 15, lgrp = lane >> 4;
  const int wg = blockIdx.x;

  f32x4 acc[4];
#pragma unroll
  for (int n = 0; n < 4; n++) acc[n] = (f32x4)0.0f;

  stage2(A, Bt, sm2, wg, 0, t);

  for (int kc = 0; kc < 8; ++kc) {
    char* cur = sm2 + (kc & 1) * 20480;
    if (kc + 1 < 8) {
      stage2(A, Bt, sm2 + ((kc + 1) & 1) * 20480, wg, kc + 1, t);
      asm volatile("s_waitcnt vmcnt(3)" ::: "memory");
    } else {
      asm volatile("s_waitcnt vmcnt(0)" ::: "memory");
    }
    __builtin_amdgcn_s_barrier();
    asm volatile("" ::: "memory");

    bfrag bf[4];
#pragma unroll
    for (int n = 0; n < 4; n++) {
      int bcol = wn * 64 + n * 16 + lrow;
      int sB = (bcol ^ (bcol >> 2)) & 3;
      bf[n] = *(const bfrag*)(cur + 4096 + bcol * 64 + ((lgrp ^ sB) << 4));
    }
    {
      int arow = wm * 16 + lrow;
      int sw = ((arow & 3) << 1) | ((arow >> 2) & 1);
      f32x4 lo = *(const f32x4*)(cur + arow * 128 + (((lgrp * 2) ^ sw) << 4));
      f32x4 hi = *(const f32x4*)(cur + arow * 128 + (((lgrp * 2 + 1) ^ sw) << 4));
      bfrag am;
      am[0] = (__bf16)lo.x; am[1] = (__bf16)lo.y; am[2] = (__bf16)lo.z; am[3] = (__bf16)lo.w;
      am[4] = (__bf16)hi.x; am[5] = (__bf16)hi.y; am[6] = (__bf16)hi.z; am[7] = (__bf16)hi.w;
#pragma unroll
      for (int n = 0; n < 4; n++)
        acc[n] = __builtin_amdgcn_mfma_f32_16x16x32_bf16(am, bf[n], acc[n], 0, 0, 0);
    }
    __builtin_amdgcn_s_barrier();
    asm volatile("" ::: "memory");
  }

  // --- T tile f32 [32][256] into LDS, then per-wave epilogue (4 rows each) ---
  float* sf = (float*)sm2;
  {
    int row = wm * 16 + lgrp * 4;
#pragma unroll
    for (int n = 0; n < 4; n++) {
      int col = wn * 64 + n * 16 + lrow;
#pragma unroll
      for (int rr = 0; rr < 4; rr++)
        sf[(row + rr) * 256 + col] = acc[n][rr];
    }
  }
  asm volatile("s_waitcnt lgkmcnt(0)" ::: "memory");
  __builtin_amdgcn_s_barrier();
  asm volatile("" ::: "memory");

  const float bb = b_bil[0];
#pragma unroll
  for (int r = 0; r < 4; ++r) {
    const int row = wid * 4 + r;
    const int b = wg * 32 + row;
    const int bp = (b == 0) ? 8190 : (b - 1);
    f32x4 tv = *(const f32x4*)(sf + row * 256 + lane * 4);
    f32x4 cv = *(const f32x4*)(C + (size_t)b * 256 + lane * 4);
    f32x4 cp = *(const f32x4*)(C + (size_t)bp * 256 + lane * 4);
    f32x4 hv = *(const f32x4*)(Hmv + (size_t)b * 256 + lane * 4);
    f32x4 d0 = hv - cv + 1e-6f;
    f32x4 d1 = hv - cp + 1e-6f;
    float s0 = tv.x * cv.x + tv.y * cv.y + tv.z * cv.z + tv.w * cv.w;
    float s1 = tv.x * cp.x + tv.y * cp.y + tv.z * cp.z + tv.w * cp.w;
    float p = d0.x * d0.x + d0.y * d0.y + d0.z * d0.z + d0.w * d0.w;
    float q = d1.x * d1.x + d1.y * d1.y + d1.z * d1.z + d1.w * d1.w;
#pragma unroll
    for (int m = 1; m < 64; m <<= 1) {
      s0 += __shfl_xor(s0, m, 64);
      s1 += __shfl_xor(s1, m, 64);
      p  += __shfl_xor(p, m, 64);
      q  += __shfl_xor(q, m, 64);
    }
    if (lane == 0) {
      out[b] = s0 + bb;
      out[8192 + b] = s1 + bb;
      out[16384 + b] = fmaxf(0.0f, sqrtf(p) - sqrtf(q) + 0.5f);
    }
  }
}

// ---------------- launch -----------------------------------------------------
extern "C" void kernel_launch(void* const* d_in, const int* in_sizes, int n_in,
                              void* d_out, int out_size, void* d_ws, size_t ws_size,
                              hipStream_t stream) {
  (void)in_sizes; (void)n_in; (void)out_size; (void)ws_size;
  const float* seq1 = (const float*)d_in[0];
  const float* adj  = (const float*)d_in[1];
  const float* Wg   = (const float*)d_in[2];
  const float* bg   = (const float*)d_in[3];
  const float* pa   = (const float*)d_in[4];
  const float* Wb   = (const float*)d_in[5];
  const float* bb   = (const float*)d_in[6];
  float* out = (float*)d_out;
  char* ws = (char*)d_ws;

  unsigned short* WgT = (unsigned short*)(ws);                 // 256 KB
  unsigned short* WbT = (unsigned short*)(ws + 262144);        // 128 KB
  float* C   = (float*)(ws + 524288);                          // 8 MB
  float* HMV = (float*)(ws + 524288 + 8388608);                // 8 MB

  hipLaunchKernelGGL(conv_w_k, dim3(512), dim3(256), 0, stream, Wg, Wb, WgT, WbT);
  hipLaunchKernelGGL(fused1_k, dim3(1024), dim3(512), 0, stream,
                     seq1, WgT, adj, bg, pa, C, HMV);
  hipLaunchKernelGGL(fused2_k, dim3(256), dim3(512), 0, stream,
                     HMV, WbT, C, HMV, bb, out);
}

// Round 7
// 102.040 us; speedup vs baseline: 2.2254x; 2.2254x over previous
//
#include <hip/hip_runtime.h>
#include <stdint.h>

typedef float f32x4 __attribute__((ext_vector_type(4)));
typedef __bf16 bfrag __attribute__((ext_vector_type(8)));
typedef unsigned short us4 __attribute__((ext_vector_type(4)));

__device__ __forceinline__ unsigned short f2bf(float f) {
  unsigned u = __float_as_uint(f);
  u += 0x7fff + ((u >> 16) & 1);   // RNE
  return (unsigned short)(u >> 16);
}
__device__ __forceinline__ float bf2f(unsigned short s) {
  return __uint_as_float(((unsigned)s) << 16);
}

typedef __attribute__((address_space(3))) void lds_vp;
typedef __attribute__((address_space(1))) void gl_vp;
__device__ __forceinline__ void gload16(const void* g, void* l) {
  __builtin_amdgcn_global_load_lds((const gl_vp*)g, (lds_vp*)l, 16, 0, 0);
}

// ---------------- kernel 0: transpose+convert weights to bf16 ----------------
__global__ __launch_bounds__(256)
void conv_w_k(const float* __restrict__ Wg, const float* __restrict__ Wb,
              unsigned short* __restrict__ WgT, unsigned short* __restrict__ WbT) {
  int i = blockIdx.x * 256 + threadIdx.x;
  if (i < 512 * 256) { int k = i >> 8, c = i & 255; WgT[c * 512 + k] = f2bf(Wg[i]); }
  if (i < 256 * 256) { int k = i >> 8, c = i & 255; WbT[c * 256 + k] = f2bf(Wb[i]); }
}

// ---------------- fused1: bf16-A-staged GEMM + adj epilogue ------------------
// BM=128 (8 batches), BN=256, BK=32. 8 waves (2x4), wave tile 64x64, acc[4][4].
// A: global f32 -> regs -> cvt -> ds_write_b128 bf16 (linear addr = t*16).
// B: global_load_lds bf16 (proven swizzle). Double-buffered 2x24KB; sf 64KB.
// LDS/chunk 88KB (was 128KB); zero cvt in K-loop.
__global__ __launch_bounds__(512, 4)
void fused1_k(const float* __restrict__ A, const unsigned short* __restrict__ Bt,
              const float* __restrict__ adj, const float* __restrict__ b_gcn,
              const float* __restrict__ prelu_a,
              float* __restrict__ Cout, float* __restrict__ Hmv) {
  __shared__ __align__(16) char sm[65536];   // buf p: A [p*24576, +8K) B [+8K, +24K); sf reuses all
  const int t = threadIdx.x;
  const int lane = t & 63;
  const int wid = t >> 6;
  const int wm = wid >> 2, wn = wid & 3;
  const int lrow = lane & 15, lgrp = lane >> 4;
  const int wg = blockIdx.x;

  // per-thread A staging source: row = t>>2 (0..127), k-seg = (t&3)*8
  const float* gA = A + (size_t)(wg * 128 + (t >> 2)) * 512 + (t & 3) * 8;
  const int aw_off = t * 16;                 // linear bf16 [128][32] dest

  // frag read offsets (constant across chunks)
  int aoff[4], boff[4];
#pragma unroll
  for (int m = 0; m < 4; m++) {
    int arow = wm * 64 + m * 16 + lrow;
    aoff[m] = arow * 64 + lgrp * 16;
  }
#pragma unroll
  for (int n = 0; n < 4; n++) {
    int bcol = wn * 64 + n * 16 + lrow;
    boff[n] = 8192 + bcol * 64 + ((lgrp ^ ((bcol ^ (bcol >> 2)) & 3)) << 4);
  }

  f32x4 acc[4][4];
#pragma unroll
  for (int m = 0; m < 4; m++)
#pragma unroll
    for (int n = 0; n < 4; n++) acc[m][n] = (f32x4)0.0f;

#define STAGE_B(buf, kc)                                                       \
  {                                                                            \
    _Pragma("unroll")                                                          \
    for (int i = 0; i < 2; i++) {                                              \
      int c = i * 512 + t;                                                     \
      int col = c >> 2, s = c & 3;                                             \
      int sp = s ^ ((col ^ (col >> 2)) & 3);                                   \
      gload16(Bt + (size_t)col * 512 + (kc) * 32 + sp * 8, (buf) + 8192 + c * 16); \
    }                                                                          \
  }

#define COMPUTE(cur)                                                           \
  {                                                                            \
    bfrag bf[4], af[4];                                                        \
    _Pragma("unroll")                                                          \
    for (int n = 0; n < 4; n++) bf[n] = *(const bfrag*)((cur) + boff[n]);      \
    _Pragma("unroll")                                                          \
    for (int m = 0; m < 4; m++) af[m] = *(const bfrag*)((cur) + aoff[m]);      \
    _Pragma("unroll")                                                          \
    for (int m = 0; m < 4; m++)                                                \
      _Pragma("unroll")                                                        \
      for (int n = 0; n < 4; n++)                                              \
        acc[m][n] = __builtin_amdgcn_mfma_f32_16x16x32_bf16(af[m], bf[n], acc[m][n], 0, 0, 0); \
  }

  // ---- prologue: stage chunk 0 ----
  {
    STAGE_B(sm, 0);
    f32x4 a0 = *(const f32x4*)(gA);
    f32x4 a1 = *(const f32x4*)(gA + 4);
    bfrag w;
    w[0] = (__bf16)a0.x; w[1] = (__bf16)a0.y; w[2] = (__bf16)a0.z; w[3] = (__bf16)a0.w;
    w[4] = (__bf16)a1.x; w[5] = (__bf16)a1.y; w[6] = (__bf16)a1.z; w[7] = (__bf16)a1.w;
    *(bfrag*)(sm + aw_off) = w;
    asm volatile("s_waitcnt vmcnt(0)" ::: "memory");
    asm volatile("s_waitcnt lgkmcnt(0)" ::: "memory");
    __builtin_amdgcn_s_barrier();
    asm volatile("" ::: "memory");
  }

  for (int kc = 0; kc < 15; ++kc) {
    char* cur = sm + (kc & 1) * 24576;
    char* nxt = sm + ((kc + 1) & 1) * 24576;
    // issue next-chunk A (regs) then B (direct-to-LDS)
    f32x4 a0 = *(const f32x4*)(gA + (kc + 1) * 32);
    f32x4 a1 = *(const f32x4*)(gA + (kc + 1) * 32 + 4);
    STAGE_B(nxt, kc + 1);

    COMPUTE(cur);

    // cvt + write next-A (compiler inserts counted vmcnt for a0/a1 here)
    bfrag w;
    w[0] = (__bf16)a0.x; w[1] = (__bf16)a0.y; w[2] = (__bf16)a0.z; w[3] = (__bf16)a0.w;
    w[4] = (__bf16)a1.x; w[5] = (__bf16)a1.y; w[6] = (__bf16)a1.z; w[7] = (__bf16)a1.w;
    *(bfrag*)(nxt + aw_off) = w;
    asm volatile("s_waitcnt vmcnt(0)" ::: "memory");       // B(kc+1) landed
    asm volatile("s_waitcnt lgkmcnt(0)" ::: "memory");     // A write visible
    __builtin_amdgcn_s_barrier();
    asm volatile("" ::: "memory");
  }
  COMPUTE(sm + 24576);   // chunk 15 (buf 1)
  __builtin_amdgcn_s_barrier();
  asm volatile("" ::: "memory");
#undef STAGE_B
#undef COMPUTE

  // --- epilogue: acc tile -> sf bf16 [128][256] (reuses all 64KB) ---
  unsigned short* sf = (unsigned short*)sm;
#pragma unroll
  for (int m = 0; m < 4; m++) {
    int row = wm * 64 + m * 16 + lgrp * 4;
#pragma unroll
    for (int n = 0; n < 4; n++) {
      int col = wn * 64 + n * 16 + lrow;
#pragma unroll
      for (int rr = 0; rr < 4; rr++)
        sf[(row + rr) * 256 + col] = f2bf(acc[m][n][rr]);
    }
  }
  asm volatile("s_waitcnt lgkmcnt(0)" ::: "memory");
  __builtin_amdgcn_s_barrier();
  asm volatile("" ::: "memory");

  // --- wave wid handles batch wg*8+wid: h1 = adj@sf + bg, PReLU, c, h_mv ---
  const float pa = prelu_a[0];
  const f32x4 bg = *(const f32x4*)(b_gcn + lane * 4);
  f32x4 sfr[16];
#pragma unroll
  for (int mm = 0; mm < 16; mm++) {
    us4 q = *(const us4*)(sf + (wid * 16 + mm) * 256 + lane * 4);
    f32x4 v;
    v.x = bf2f(q.x); v.y = bf2f(q.y); v.z = bf2f(q.z); v.w = bf2f(q.w);
    sfr[mm] = v;
  }
  const int b = wg * 8 + wid;
  const float* adjb = adj + (size_t)b * 256;
  f32x4 cacc = (f32x4)0.0f;
  f32x4 hmv = (f32x4)0.0f;
#pragma unroll
  for (int n = 0; n < 16; n++) {
    f32x4 a4 = (f32x4)0.0f;
#pragma unroll
    for (int m = 0; m < 16; m++) a4 += adjb[n * 16 + m] * sfr[m];
    a4 += bg;
    f32x4 hv;
    hv.x = a4.x >= 0.f ? a4.x : pa * a4.x;
    hv.y = a4.y >= 0.f ? a4.y : pa * a4.y;
    hv.z = a4.z >= 0.f ? a4.z : pa * a4.z;
    hv.w = a4.w >= 0.f ? a4.w : pa * a4.w;
    if (n < 15) cacc += hv; else hmv = hv;
  }
  cacc *= (1.0f / 15.0f);
  *(f32x4*)(Cout + (size_t)b * 256 + lane * 4) = cacc;
  *(f32x4*)(Hmv + (size_t)b * 256 + lane * 4) = hmv;
}

// ---------------- fused2: T = HMV@WbT (K=256) + bilinear + norms + loss ------
// BM=32 batches, BN=256, BK=32, grid 256. 8 waves (2x4), wave tile 16x64
// (acc[1][4]). LDS 2 x (A 4KB | B 16KB) = 40KB static, gload_lds staging.
__device__ __forceinline__ void stage2(const float* __restrict__ A,
                                       const unsigned short* __restrict__ Bt,
                                       char* buf, int wg, int kc, int t) {
  {
    int c = t & 255;                 // A: 32 rows x 32 f32 (4KB); dup per half
    int row = c >> 3, s = c & 7;
    int sp = s ^ (((row & 3) << 1) | ((row >> 2) & 1));
    gload16(A + (size_t)(wg * 32 + row) * 256 + kc * 32 + sp * 4, buf + c * 16);
  }
#pragma unroll
  for (int i = 0; i < 2; i++) {      // B: 256 cols x 32 bf16 (16KB)
    int c = i * 512 + t;
    int col = c >> 2, s = c & 3;
    int sp = s ^ ((col ^ (col >> 2)) & 3);
    gload16(Bt + (size_t)col * 256 + kc * 32 + sp * 8, buf + 4096 + c * 16);
  }
}

__global__ __launch_bounds__(512)
void fused2_k(const float* __restrict__ A, const unsigned short* __restrict__ Bt,
              const float* __restrict__ C, const float* __restrict__ Hmv,
              const float* __restrict__ b_bil, float* __restrict__ out) {
  __shared__ __align__(16) char sm2[40960];
  const int t = threadIdx.x;
  const int lane = t & 63;
  const int wid = t >> 6;
  const int wm = wid >> 2, wn = wid & 3;
  const int lrow = lane & 15, lgrp = lane >> 4;
  const int wg = blockIdx.x;

  f32x4 acc[4];
#pragma unroll
  for (int n = 0; n < 4; n++) acc[n] = (f32x4)0.0f;

  stage2(A, Bt, sm2, wg, 0, t);

  for (int kc = 0; kc < 8; ++kc) {
    char* cur = sm2 + (kc & 1) * 20480;
    if (kc + 1 < 8) {
      stage2(A, Bt, sm2 + ((kc + 1) & 1) * 20480, wg, kc + 1, t);
      asm volatile("s_waitcnt vmcnt(3)" ::: "memory");
    } else {
      asm volatile("s_waitcnt vmcnt(0)" ::: "memory");
    }
    __builtin_amdgcn_s_barrier();
    asm volatile("" ::: "memory");

    bfrag bf[4];
#pragma unroll
    for (int n = 0; n < 4; n++) {
      int bcol = wn * 64 + n * 16 + lrow;
      int sB = (bcol ^ (bcol >> 2)) & 3;
      bf[n] = *(const bfrag*)(cur + 4096 + bcol * 64 + ((lgrp ^ sB) << 4));
    }
    {
      int arow = wm * 16 + lrow;
      int sw = ((arow & 3) << 1) | ((arow >> 2) & 1);
      f32x4 lo = *(const f32x4*)(cur + arow * 128 + (((lgrp * 2) ^ sw) << 4));
      f32x4 hi = *(const f32x4*)(cur + arow * 128 + (((lgrp * 2 + 1) ^ sw) << 4));
      bfrag am;
      am[0] = (__bf16)lo.x; am[1] = (__bf16)lo.y; am[2] = (__bf16)lo.z; am[3] = (__bf16)lo.w;
      am[4] = (__bf16)hi.x; am[5] = (__bf16)hi.y; am[6] = (__bf16)hi.z; am[7] = (__bf16)hi.w;
#pragma unroll
      for (int n = 0; n < 4; n++)
        acc[n] = __builtin_amdgcn_mfma_f32_16x16x32_bf16(am, bf[n], acc[n], 0, 0, 0);
    }
    __builtin_amdgcn_s_barrier();
    asm volatile("" ::: "memory");
  }

  // --- T tile f32 [32][256] into LDS, then per-wave epilogue (4 rows each) ---
  float* sf = (float*)sm2;
  {
    int row = wm * 16 + lgrp * 4;
#pragma unroll
    for (int n = 0; n < 4; n++) {
      int col = wn * 64 + n * 16 + lrow;
#pragma unroll
      for (int rr = 0; rr < 4; rr++)
        sf[(row + rr) * 256 + col] = acc[n][rr];
    }
  }
  asm volatile("s_waitcnt lgkmcnt(0)" ::: "memory");
  __builtin_amdgcn_s_barrier();
  asm volatile("" ::: "memory");

  const float bb = b_bil[0];
#pragma unroll
  for (int r = 0; r < 4; ++r) {
    const int row = wid * 4 + r;
    const int b = wg * 32 + row;
    const int bp = (b == 0) ? 8190 : (b - 1);
    f32x4 tv = *(const f32x4*)(sf + row * 256 + lane * 4);
    f32x4 cv = *(const f32x4*)(C + (size_t)b * 256 + lane * 4);
    f32x4 cp = *(const f32x4*)(C + (size_t)bp * 256 + lane * 4);
    f32x4 hv = *(const f32x4*)(Hmv + (size_t)b * 256 + lane * 4);
    f32x4 d0 = hv - cv + 1e-6f;
    f32x4 d1 = hv - cp + 1e-6f;
    float s0 = tv.x * cv.x + tv.y * cv.y + tv.z * cv.z + tv.w * cv.w;
    float s1 = tv.x * cp.x + tv.y * cp.y + tv.z * cp.z + tv.w * cp.w;
    float p = d0.x * d0.x + d0.y * d0.y + d0.z * d0.z + d0.w * d0.w;
    float q = d1.x * d1.x + d1.y * d1.y + d1.z * d1.z + d1.w * d1.w;
#pragma unroll
    for (int m = 1; m < 64; m <<= 1) {
      s0 += __shfl_xor(s0, m, 64);
      s1 += __shfl_xor(s1, m, 64);
      p  += __shfl_xor(p, m, 64);
      q  += __shfl_xor(q, m, 64);
    }
    if (lane == 0) {
      out[b] = s0 + bb;
      out[8192 + b] = s1 + bb;
      out[16384 + b] = fmaxf(0.0f, sqrtf(p) - sqrtf(q) + 0.5f);
    }
  }
}

// ---------------- launch -----------------------------------------------------
extern "C" void kernel_launch(void* const* d_in, const int* in_sizes, int n_in,
                              void* d_out, int out_size, void* d_ws, size_t ws_size,
                              hipStream_t stream) {
  (void)in_sizes; (void)n_in; (void)out_size; (void)ws_size;
  const float* seq1 = (const float*)d_in[0];
  const float* adj  = (const float*)d_in[1];
  const float* Wg   = (const float*)d_in[2];
  const float* bg   = (const float*)d_in[3];
  const float* pa   = (const float*)d_in[4];
  const float* Wb   = (const float*)d_in[5];
  const float* bb   = (const float*)d_in[6];
  float* out = (float*)d_out;
  char* ws = (char*)d_ws;

  unsigned short* WgT = (unsigned short*)(ws);                 // 256 KB
  unsigned short* WbT = (unsigned short*)(ws + 262144);        // 128 KB
  float* C   = (float*)(ws + 524288);                          // 8 MB
  float* HMV = (float*)(ws + 524288 + 8388608);                // 8 MB

  hipLaunchKernelGGL(conv_w_k, dim3(512), dim3(256), 0, stream, Wg, Wb, WgT, WbT);
  hipLaunchKernelGGL(fused1_k, dim3(1024), dim3(512), 0, stream,
                     seq1, WgT, adj, bg, pa, C, HMV);
  hipLaunchKernelGGL(fused2_k, dim3(256), dim3(512), 0, stream,
                     HMV, WbT, C, HMV, bb, out);
}

// Round 8
// 99.881 us; speedup vs baseline: 2.2735x; 1.0216x over previous
//
#include <hip/hip_runtime.h>
#include <stdint.h>

typedef float f32x4 __attribute__((ext_vector_type(4)));
typedef __bf16 bfrag __attribute__((ext_vector_type(8)));
typedef unsigned short us4 __attribute__((ext_vector_type(4)));

__device__ __forceinline__ unsigned short f2bf(float f) {
  unsigned u = __float_as_uint(f);
  u += 0x7fff + ((u >> 16) & 1);   // RNE
  return (unsigned short)(u >> 16);
}
__device__ __forceinline__ float bf2f(unsigned short s) {
  return __uint_as_float(((unsigned)s) << 16);
}

typedef __attribute__((address_space(3))) void lds_vp;
typedef __attribute__((address_space(1))) void gl_vp;
__device__ __forceinline__ void gload16(const void* g, void* l) {
  __builtin_amdgcn_global_load_lds((const gl_vp*)g, (lds_vp*)l, 16, 0, 0);
}

// ---------------- kernel 0: transpose+convert weights to bf16 ----------------
__global__ __launch_bounds__(256)
void conv_w_k(const float* __restrict__ Wg, const float* __restrict__ Wb,
              unsigned short* __restrict__ WgT, unsigned short* __restrict__ WbT) {
  int i = blockIdx.x * 256 + threadIdx.x;
  if (i < 512 * 256) { int k = i >> 8, c = i & 255; WgT[c * 512 + k] = f2bf(Wg[i]); }
  if (i < 256 * 256) { int k = i >> 8, c = i & 255; WbT[c * 256 + k] = f2bf(Wb[i]); }
}

// ---------------- fused1: depth-2 pipelined GEMM + adj epilogue --------------
// BM=128 (8 batches), BN=256, BK=32. 8 waves (2x4), wave tile 64x64, acc[4][4].
// Triple-buffered LDS (3 x 24KB: A bf16 8KB + B bf16 16KB). Phase kc issues
// A(kc+2) (regs->cvt->ds_write, consumed in-phase) then B(kc+2) (gload_lds).
// The cvt's implicit vmcnt leaves only B(kc+2) outstanding => B(kc+1) landed,
// B(kc+2) stays in flight across the next phase (depth-2 counted pipeline).
// A LDS layout: [128 rows][4 chunks of 16B], chunk' = chunk ^ ((row>>1)&3)
// -> fragment reads are 2-way bank access (free).
__global__ __launch_bounds__(512, 4)
void fused1_k(const float* __restrict__ A, const unsigned short* __restrict__ Bt,
              const float* __restrict__ adj, const float* __restrict__ b_gcn,
              const float* __restrict__ prelu_a,
              float* __restrict__ Cout, float* __restrict__ Hmv) {
  __shared__ __align__(16) char sm[73728];   // 3 buffers x 24576
  const int t = threadIdx.x;
  const int lane = t & 63;
  const int wid = t >> 6;
  const int wm = wid >> 2, wn = wid & 3;
  const int lrow = lane & 15, lgrp = lane >> 4;
  const int wg = blockIdx.x;

  // A staging: thread t covers row t>>2, 8 f32 at col (t&3)*8
  const int arw = t >> 2;
  const float* gA = A + (size_t)(wg * 128 + arw) * 512 + (t & 3) * 8;
  const int awr = arw * 64 + (((t & 3) ^ ((arw >> 1) & 3)) << 4);  // swizzled dest

  // fragment read offsets (constant across chunks)
  int aoff[4], boff[4];
#pragma unroll
  for (int m = 0; m < 4; m++) {
    int arow = wm * 64 + m * 16 + lrow;
    aoff[m] = arow * 64 + ((lgrp ^ ((arow >> 1) & 3)) << 4);
  }
#pragma unroll
  for (int n = 0; n < 4; n++) {
    int bcol = wn * 64 + n * 16 + lrow;
    boff[n] = 8192 + bcol * 64 + ((lgrp ^ ((bcol ^ (bcol >> 2)) & 3)) << 4);
  }

  f32x4 acc[4][4];
#pragma unroll
  for (int m = 0; m < 4; m++)
#pragma unroll
    for (int n = 0; n < 4; n++) acc[m][n] = (f32x4)0.0f;

#define STAGE_B(buf, kc)                                                       \
  {                                                                            \
    _Pragma("unroll")                                                          \
    for (int i = 0; i < 2; i++) {                                              \
      int c = i * 512 + t;                                                     \
      int col = c >> 2, s = c & 3;                                             \
      int sp = s ^ ((col ^ (col >> 2)) & 3);                                   \
      gload16(Bt + (size_t)col * 512 + (kc) * 32 + sp * 8, (buf) + 8192 + c * 16); \
    }                                                                          \
  }

#define CVT_WRITE_A(buf, a0, a1)                                               \
  {                                                                            \
    bfrag w;                                                                   \
    w[0] = (__bf16)(a0).x; w[1] = (__bf16)(a0).y;                              \
    w[2] = (__bf16)(a0).z; w[3] = (__bf16)(a0).w;                              \
    w[4] = (__bf16)(a1).x; w[5] = (__bf16)(a1).y;                              \
    w[6] = (__bf16)(a1).z; w[7] = (__bf16)(a1).w;                              \
    *(bfrag*)((buf) + awr) = w;                                                \
  }

#define COMPUTE(cur)                                                           \
  {                                                                            \
    bfrag bf[4], af[4];                                                        \
    _Pragma("unroll")                                                          \
    for (int n = 0; n < 4; n++) bf[n] = *(const bfrag*)((cur) + boff[n]);      \
    _Pragma("unroll")                                                          \
    for (int m = 0; m < 4; m++) af[m] = *(const bfrag*)((cur) + aoff[m]);      \
    _Pragma("unroll")                                                          \
    for (int m = 0; m < 4; m++)                                                \
      _Pragma("unroll")                                                        \
      for (int n = 0; n < 4; n++)                                              \
        acc[m][n] = __builtin_amdgcn_mfma_f32_16x16x32_bf16(af[m], bf[n], acc[m][n], 0, 0, 0); \
  }

  // ---- prologue: stage chunks 0 and 1 (A loads first in vm queue) ----
  {
    f32x4 p0 = *(const f32x4*)(gA);
    f32x4 p1 = *(const f32x4*)(gA + 4);
    f32x4 q0 = *(const f32x4*)(gA + 32);
    f32x4 q1 = *(const f32x4*)(gA + 36);
    __builtin_amdgcn_sched_barrier(0);
    STAGE_B(sm, 0);
    STAGE_B(sm + 24576, 1);
    __builtin_amdgcn_sched_barrier(0);
    CVT_WRITE_A(sm, p0, p1);
    CVT_WRITE_A(sm + 24576, q0, q1);
    asm volatile("s_waitcnt vmcnt(2)" ::: "memory");   // B(0) landed; B(1) in flight
    asm volatile("s_waitcnt lgkmcnt(0)" ::: "memory");
    __builtin_amdgcn_s_barrier();
    asm volatile("" ::: "memory");
  }

#pragma unroll
  for (int kc = 0; kc < 16; ++kc) {
    char* cur = sm + (kc % 3) * 24576;
    char* nxt = sm + ((kc + 2) % 3) * 24576;
    f32x4 a0, a1;
    if (kc < 14) {
      a0 = *(const f32x4*)(gA + (kc + 2) * 32);
      a1 = *(const f32x4*)(gA + (kc + 2) * 32 + 4);
      __builtin_amdgcn_sched_barrier(0);
      STAGE_B(nxt, kc + 2);
      __builtin_amdgcn_sched_barrier(0);
    }
    COMPUTE(cur);
    if (kc < 14) {
      // compiler waits for a0/a1 here (vmcnt(2)) => B(kc+1) landed,
      // B(kc+2) remains in flight.
      CVT_WRITE_A(nxt, a0, a1);
      asm volatile("s_waitcnt lgkmcnt(0)" ::: "memory");
    } else if (kc == 14) {
      asm volatile("s_waitcnt vmcnt(0)" ::: "memory");  // B(15) landed
    }
    __builtin_amdgcn_s_barrier();
    asm volatile("" ::: "memory");
  }
#undef STAGE_B
#undef CVT_WRITE_A
#undef COMPUTE

  // --- epilogue: acc tile -> sf bf16 [128][256] (reuses staging LDS) ---
  unsigned short* sf = (unsigned short*)sm;
#pragma unroll
  for (int m = 0; m < 4; m++) {
    int row = wm * 64 + m * 16 + lgrp * 4;
#pragma unroll
    for (int n = 0; n < 4; n++) {
      int col = wn * 64 + n * 16 + lrow;
#pragma unroll
      for (int rr = 0; rr < 4; rr++)
        sf[(row + rr) * 256 + col] = f2bf(acc[m][n][rr]);
    }
  }
  asm volatile("s_waitcnt lgkmcnt(0)" ::: "memory");
  __builtin_amdgcn_s_barrier();
  asm volatile("" ::: "memory");

  // --- wave wid handles batch wg*8+wid: h1 = adj@sf + bg, PReLU, c, h_mv ---
  const float pa = prelu_a[0];
  const f32x4 bg = *(const f32x4*)(b_gcn + lane * 4);
  f32x4 sfr[16];
#pragma unroll
  for (int mm = 0; mm < 16; mm++) {
    us4 q = *(const us4*)(sf + (wid * 16 + mm) * 256 + lane * 4);
    f32x4 v;
    v.x = bf2f(q.x); v.y = bf2f(q.y); v.z = bf2f(q.z); v.w = bf2f(q.w);
    sfr[mm] = v;
  }
  const int b = wg * 8 + wid;
  const float* adjb = adj + (size_t)b * 256;
  f32x4 cacc = (f32x4)0.0f;
  f32x4 hmv = (f32x4)0.0f;
#pragma unroll
  for (int n = 0; n < 16; n++) {
    f32x4 a4 = (f32x4)0.0f;
#pragma unroll
    for (int m = 0; m < 16; m++) a4 += adjb[n * 16 + m] * sfr[m];
    a4 += bg;
    f32x4 hv;
    hv.x = a4.x >= 0.f ? a4.x : pa * a4.x;
    hv.y = a4.y >= 0.f ? a4.y : pa * a4.y;
    hv.z = a4.z >= 0.f ? a4.z : pa * a4.z;
    hv.w = a4.w >= 0.f ? a4.w : pa * a4.w;
    if (n < 15) cacc += hv; else hmv = hv;
  }
  cacc *= (1.0f / 15.0f);
  *(f32x4*)(Cout + (size_t)b * 256 + lane * 4) = cacc;
  *(f32x4*)(Hmv + (size_t)b * 256 + lane * 4) = hmv;
}

// ---------------- fused2: T = HMV@WbT (K=256) + bilinear + norms + loss ------
// BM=32 batches, BN=256, BK=32, grid 256. 8 waves (2x4), wave tile 16x64
// (acc[1][4]). LDS 2 x (A 4KB | B 16KB) = 40KB static, gload_lds staging.
__device__ __forceinline__ void stage2(const float* __restrict__ A,
                                       const unsigned short* __restrict__ Bt,
                                       char* buf, int wg, int kc, int t) {
  {
    int c = t & 255;                 // A: 32 rows x 32 f32 (4KB); dup per half
    int row = c >> 3, s = c & 7;
    int sp = s ^ (((row & 3) << 1) | ((row >> 2) & 1));
    gload16(A + (size_t)(wg * 32 + row) * 256 + kc * 32 + sp * 4, buf + c * 16);
  }
#pragma unroll
  for (int i = 0; i < 2; i++) {      // B: 256 cols x 32 bf16 (16KB)
    int c = i * 512 + t;
    int col = c >> 2, s = c & 3;
    int sp = s ^ ((col ^ (col >> 2)) & 3);
    gload16(Bt + (size_t)col * 256 + kc * 32 + sp * 8, buf + 4096 + c * 16);
  }
}

__global__ __launch_bounds__(512)
void fused2_k(const float* __restrict__ A, const unsigned short* __restrict__ Bt,
              const float* __restrict__ C, const float* __restrict__ Hmv,
              const float* __restrict__ b_bil, float* __restrict__ out) {
  __shared__ __align__(16) char sm2[40960];
  const int t = threadIdx.x;
  const int lane = t & 63;
  const int wid = t >> 6;
  const int wm = wid >> 2, wn = wid & 3;
  const int lrow = lane & 15, lgrp = lane >> 4;
  const int wg = blockIdx.x;

  f32x4 acc[4];
#pragma unroll
  for (int n = 0; n < 4; n++) acc[n] = (f32x4)0.0f;

  stage2(A, Bt, sm2, wg, 0, t);

  for (int kc = 0; kc < 8; ++kc) {
    char* cur = sm2 + (kc & 1) * 20480;
    if (kc + 1 < 8) {
      stage2(A, Bt, sm2 + ((kc + 1) & 1) * 20480, wg, kc + 1, t);
      asm volatile("s_waitcnt vmcnt(3)" ::: "memory");
    } else {
      asm volatile("s_waitcnt vmcnt(0)" ::: "memory");
    }
    __builtin_amdgcn_s_barrier();
    asm volatile("" ::: "memory");

    bfrag bf[4];
#pragma unroll
    for (int n = 0; n < 4; n++) {
      int bcol = wn * 64 + n * 16 + lrow;
      int sB = (bcol ^ (bcol >> 2)) & 3;
      bf[n] = *(const bfrag*)(cur + 4096 + bcol * 64 + ((lgrp ^ sB) << 4));
    }
    {
      int arow = wm * 16 + lrow;
      int sw = ((arow & 3) << 1) | ((arow >> 2) & 1);
      f32x4 lo = *(const f32x4*)(cur + arow * 128 + (((lgrp * 2) ^ sw) << 4));
      f32x4 hi = *(const f32x4*)(cur + arow * 128 + (((lgrp * 2 + 1) ^ sw) << 4));
      bfrag am;
      am[0] = (__bf16)lo.x; am[1] = (__bf16)lo.y; am[2] = (__bf16)lo.z; am[3] = (__bf16)lo.w;
      am[4] = (__bf16)hi.x; am[5] = (__bf16)hi.y; am[6] = (__bf16)hi.z; am[7] = (__bf16)hi.w;
#pragma unroll
      for (int n = 0; n < 4; n++)
        acc[n] = __builtin_amdgcn_mfma_f32_16x16x32_bf16(am, bf[n], acc[n], 0, 0, 0);
    }
    __builtin_amdgcn_s_barrier();
    asm volatile("" ::: "memory");
  }

  // --- T tile f32 [32][256] into LDS, then per-wave epilogue (4 rows each) ---
  float* sf = (float*)sm2;
  {
    int row = wm * 16 + lgrp * 4;
#pragma unroll
    for (int n = 0; n < 4; n++) {
      int col = wn * 64 + n * 16 + lrow;
#pragma unroll
      for (int rr = 0; rr < 4; rr++)
        sf[(row + rr) * 256 + col] = acc[n][rr];
    }
  }
  asm volatile("s_waitcnt lgkmcnt(0)" ::: "memory");
  __builtin_amdgcn_s_barrier();
  asm volatile("" ::: "memory");

  const float bb = b_bil[0];
#pragma unroll
  for (int r = 0; r < 4; ++r) {
    const int row = wid * 4 + r;
    const int b = wg * 32 + row;
    const int bp = (b == 0) ? 8190 : (b - 1);
    f32x4 tv = *(const f32x4*)(sf + row * 256 + lane * 4);
    f32x4 cv = *(const f32x4*)(C + (size_t)b * 256 + lane * 4);
    f32x4 cp = *(const f32x4*)(C + (size_t)bp * 256 + lane * 4);
    f32x4 hv = *(const f32x4*)(Hmv + (size_t)b * 256 + lane * 4);
    f32x4 d0 = hv - cv + 1e-6f;
    f32x4 d1 = hv - cp + 1e-6f;
    float s0 = tv.x * cv.x + tv.y * cv.y + tv.z * cv.z + tv.w * cv.w;
    float s1 = tv.x * cp.x + tv.y * cp.y + tv.z * cp.z + tv.w * cp.w;
    float p = d0.x * d0.x + d0.y * d0.y + d0.z * d0.z + d0.w * d0.w;
    float q = d1.x * d1.x + d1.y * d1.y + d1.z * d1.z + d1.w * d1.w;
#pragma unroll
    for (int m = 1; m < 64; m <<= 1) {
      s0 += __shfl_xor(s0, m, 64);
      s1 += __shfl_xor(s1, m, 64);
      p  += __shfl_xor(p, m, 64);
      q  += __shfl_xor(q, m, 64);
    }
    if (lane == 0) {
      out[b] = s0 + bb;
      out[8192 + b] = s1 + bb;
      out[16384 + b] = fmaxf(0.0f, sqrtf(p) - sqrtf(q) + 0.5f);
    }
  }
}

// ---------------- launch -----------------------------------------------------
extern "C" void kernel_launch(void* const* d_in, const int* in_sizes, int n_in,
                              void* d_out, int out_size, void* d_ws, size_t ws_size,
                              hipStream_t stream) {
  (void)in_sizes; (void)n_in; (void)out_size; (void)ws_size;
  const float* seq1 = (const float*)d_in[0];
  const float* adj  = (const float*)d_in[1];
  const float* Wg   = (const float*)d_in[2];
  const float* bg   = (const float*)d_in[3];
  const float* pa   = (const float*)d_in[4];
  const float* Wb   = (const float*)d_in[5];
  const float* bb   = (const float*)d_in[6];
  float* out = (float*)d_out;
  char* ws = (char*)d_ws;

  unsigned short* WgT = (unsigned short*)(ws);                 // 256 KB
  unsigned short* WbT = (unsigned short*)(ws + 262144);        // 128 KB
  float* C   = (float*)(ws + 524288);                          // 8 MB
  float* HMV = (float*)(ws + 524288 + 8388608);                // 8 MB

  hipLaunchKernelGGL(conv_w_k, dim3(512), dim3(256), 0, stream, Wg, Wb, WgT, WbT);
  hipLaunchKernelGGL(fused1_k, dim3(1024), dim3(512), 0, stream,
                     seq1, WgT, adj, bg, pa, C, HMV);
  hipLaunchKernelGGL(fused2_k, dim3(256), dim3(512), 0, stream,
                     HMV, WbT, C, HMV, bb, out);
}